// Round 7
// baseline (936.281 us; speedup 1.0000x reference)
//
#include <hip/hip_runtime.h>
#include <hip/hip_bf16.h>
#include <cstdint>
#include <cstddef>

// Problem dims (fixed by reference)
#define T_STEPS 500
#define BATCH   128
#define FDIM    128
#define HDIM    512
#define ODIM    32
#define M_ROWS  (T_STEPS * BATCH)   // 64000
#define ZOFF    (512u << 11)        // zero-row byte offset, fp32 WrecT (2 KB rows)
#define ZOFFB   (512u << 10)        // zero-row byte offset, bf16 WrecTb (1 KB rows)

typedef __attribute__((ext_vector_type(8))) __bf16 bf16x8;
typedef __attribute__((ext_vector_type(4))) float  f32x4;

__device__ __forceinline__ float bfbits2f(unsigned short u) {
    union { unsigned int i; float f; } c; c.i = ((unsigned int)u) << 16; return c.f;
}
__device__ __forceinline__ float asf(unsigned int u) {
    union { unsigned int i; float f; } c; c.i = u; return c.f;
}
// LDS-only barrier: does NOT drain vmcnt (global loads/stores stay in flight).
// Safe iff all cross-thread communication inside the kernel is via LDS.
__device__ __forceinline__ void lds_barrier() {
    asm volatile("s_waitcnt lgkmcnt(0)\n\ts_barrier" ::: "memory");
}

// ---------------------------------------------------------------------------
// Dtype detect: flag=1 means fp32 inputs, flag=0 means bf16.
// (Measured on this harness: flag==1 — fp32. bf16 path kept for robustness.)
// ---------------------------------------------------------------------------
__global__ void detect_kernel(const unsigned short* __restrict__ xw, int* __restrict__ flag) {
    __shared__ int cnt;
    if (threadIdx.x == 0) cnt = 0;
    __syncthreads();
    unsigned short w = xw[threadIdx.x * 2];
    int e = (w >> 7) & 0xFF;
    if (e >= 170) atomicAdd(&cnt, 1);
    __syncthreads();
    if (threadIdx.x == 0) *flag = (cnt >= 8) ? 1 : 0;
}

// ---------------------------------------------------------------------------
// Prep. flag==1 (fp32): WrecT fp32 transpose (+zero row), WinT fp32 transpose.
//       flag==0 (bf16): WrecTb raw bf16-bit transpose (+zero row).
// WoutT (fp32 [h][o]) and bout32 built either way.
// ---------------------------------------------------------------------------
__global__ void prep_kernel(const void* __restrict__ Wrec,
                            const void* __restrict__ Wout,
                            const void* __restrict__ bout,
                            const void* __restrict__ Win,
                            const int* __restrict__ flag,
                            float* __restrict__ WrecT,
                            unsigned short* __restrict__ WrecTb,
                            float* __restrict__ WoutT,
                            float* __restrict__ WinT,
                            float* __restrict__ bout32) {
    const int fp32 = *flag;
    int idx = blockIdx.x * blockDim.x + threadIdx.x;
    if (fp32) {
        if (idx < HDIM * HDIM) {
            int h = idx / HDIM, hp = idx % HDIM;
            WrecT[hp * HDIM + h] = ((const float*)Wrec)[idx];
        }
        if (idx < HDIM) WrecT[HDIM * HDIM + idx] = 0.f;
        if (idx < HDIM * FDIM) {
            int h = idx / FDIM, f = idx % FDIM;
            WinT[f * HDIM + h] = ((const float*)Win)[idx];
        }
    } else {
        if (idx < HDIM * HDIM) {
            int h = idx / HDIM, hp = idx % HDIM;
            WrecTb[hp * HDIM + h] = ((const unsigned short*)Wrec)[idx];
        }
        if (idx < HDIM) WrecTb[HDIM * HDIM + idx] = 0;
    }
    if (idx < ODIM * HDIM) {
        int o = idx / HDIM, h = idx % HDIM;
        WoutT[h * ODIM + o] = fp32 ? ((const float*)Wout)[idx]
                                   : bfbits2f(((const unsigned short*)Wout)[idx]);
    }
    if (idx < ODIM)
        bout32[idx] = fp32 ? ((const float*)bout)[idx]
                           : bfbits2f(((const unsigned short*)bout)[idx]);
}

// ---------------------------------------------------------------------------
// i_in GEMM, MFMA path (flag==0 / bf16 only — dead on this harness).
// ---------------------------------------------------------------------------
__global__ __launch_bounds__(256) void iin_gemm_mfma(const __hip_bfloat16* __restrict__ x,
                                                     const __hip_bfloat16* __restrict__ Win,
                                                     const int* __restrict__ flag,
                                                     float* __restrict__ iin) {
    if (*flag != 0) return;
    const int mt   = blockIdx.x;
    const int nt   = blockIdx.y;
    const int wave = threadIdx.x >> 6;
    const int lane = threadIdx.x & 63;
    const int l15  = lane & 15;
    const int quad = lane >> 4;
    const int m_base = mt * 64 + wave * 16;
    const int n_base = nt * 64;

    const __bf16* xb = reinterpret_cast<const __bf16*>(x);
    const __bf16* wb = reinterpret_cast<const __bf16*>(Win);

    f32x4 acc[4] = {{0.f,0.f,0.f,0.f},{0.f,0.f,0.f,0.f},{0.f,0.f,0.f,0.f},{0.f,0.f,0.f,0.f}};

#pragma unroll
    for (int kk = 0; kk < 4; ++kk) {
        const int k0 = kk * 32 + quad * 8;
        bf16x8 a = *reinterpret_cast<const bf16x8*>(xb + (size_t)(m_base + l15) * FDIM + k0);
#pragma unroll
        for (int nb = 0; nb < 4; ++nb) {
            bf16x8 bf = *reinterpret_cast<const bf16x8*>(wb + (size_t)(n_base + nb * 16 + l15) * FDIM + k0);
            acc[nb] = __builtin_amdgcn_mfma_f32_16x16x32_bf16(a, bf, acc[nb], 0, 0, 0);
        }
    }

#pragma unroll
    for (int nb = 0; nb < 4; ++nb)
#pragma unroll
        for (int r = 0; r < 4; ++r)
            iin[(size_t)(m_base + quad * 4 + r) * HDIM + n_base + nb * 16 + l15] = acc[nb][r];
}

// ---------------------------------------------------------------------------
// i_in GEMM, fp32 VALU path (flag==1 — the live path).
// ---------------------------------------------------------------------------
__global__ __launch_bounds__(256) void iin_gemm_valu(const void* __restrict__ x,
                                                     const float* __restrict__ WinT,
                                                     const int* __restrict__ flag,
                                                     float* __restrict__ iin) {
    if (*flag != 1) return;
    const int tid  = threadIdx.x;
    const int m0   = blockIdx.x * 32;

    __shared__ float xs[32][FDIM];   // 16 KB

    for (int i = tid; i < 32 * FDIM; i += 256)
        xs[0][i] = ((const float*)x)[(size_t)m0 * FDIM + i];
    __syncthreads();

    float acc[32][2];
#pragma unroll
    for (int m = 0; m < 32; ++m) { acc[m][0] = 0.f; acc[m][1] = 0.f; }

#pragma unroll 4
    for (int k = 0; k < FDIM; ++k) {
        float w0 = WinT[(size_t)k * HDIM + tid];
        float w1 = WinT[(size_t)k * HDIM + 256 + tid];
#pragma unroll
        for (int m = 0; m < 32; ++m) {
            float xv = xs[m][k];
            acc[m][0] += xv * w0;
            acc[m][1] += xv * w1;
        }
    }

#pragma unroll
    for (int m = 0; m < 32; ++m) {
        iin[(size_t)(m0 + m) * HDIM + tid]       = acc[m][0];
        iin[(size_t)(m0 + m) * HDIM + 256 + tid] = acc[m][1];
    }
}

// ---------------------------------------------------------------------------
// Scan, fp32 weights (flag==1 — LIVE). 128 WGs, 1024 threads.
// vs R5: (a) raw LDS-only barriers — no vmcnt(0) drain, so the iin load and
// masksG store stay in flight across barriers; (b) iin prefetched one step
// ahead (full-step slack); (c) 3-deep pipelined gather (12 float4 loads in
// flight). Accumulation order identical to R5 (group-sequential ascending).
// ---------------------------------------------------------------------------
__global__ __launch_bounds__(1024) void scan_f32(const float* __restrict__ iin,
                                                 const float* __restrict__ WrecT,
                                                 const int* __restrict__ flag,
                                                 unsigned long long* __restrict__ masksG) {
    if (*flag != 1) return;
    const int b    = blockIdx.x;
    const int tid  = threadIdx.x;
    const int q    = tid & 127;         // h-quad 4q..4q+3 for gather
    const int p    = tid >> 7;          // parity class 0..7
    const int lane = tid & 63;
    const int wv   = tid >> 6;
    const bool st  = tid < HDIM;        // state-owning threads
    const int h    = tid;

    __shared__ unsigned long long wmask[8];
    __shared__ float4 part[8][128];
    __shared__ alignas(16) unsigned int slA[8][68];
    __shared__ alignas(16) unsigned int slB[8][68];
    unsigned int (*slO)[68] = slA;
    unsigned int (*slN)[68] = slB;

    float v = 0.f, cur = 0.f, a = 0.f;
    int   cnt = 0;
    const char* WQ = (const char*)WrecT + q * 16;
    float ic_cur = st ? iin[(size_t)b * HDIM + h] : 0.f;   // t = 0 (pre-loop)

    for (int t = 0; t < T_STEPS; ++t) {
        // prefetch next step's feed-forward current (~full step of slack)
        float ic_next = 0.f;
        if (st && (t + 1) < T_STEPS)
            ic_next = iin[((size_t)(t + 1) * BATCH + b) * HDIM + h];

        float i_dec = 0.f; bool zk = false; unsigned long long m = 0;
        if (st) {
            float s = (0.0f - v) + 0.5f * expf((v - 1.0f) * 2.0f);
            s = s + cur;
            s = s - a;
            float v_dec = v + 0.1f * s;
            i_dec = cur - 0.2f * cur;
            float a_dec = a + 0.002f * (4.0f * v - a);
            zk = (v_dec - 1.0f) > 0.0f;
            m = __ballot(zk);
            if (lane == 0) {
                wmask[wv] = m;
                masksG[((size_t)t * BATCH + b) * 8 + wv] = m;   // fire-and-forget
            }
            v = zk ? 0.0f : v_dec;
            a = zk ? (a_dec + 0.02f) : a_dec;
        }

        // ---- 3-deep pipelined gather over my parity class of PREV spikes ----
        float4 rs = {0.f, 0.f, 0.f, 0.f};
        {
            const int n  = (cnt + 7 - p) >> 3;      // my sub-list length
            const int ng = (n + 3) >> 2;            // padded groups of 4
            float4 b0[4], b1[4], b2[4];
            auto ld4 = [&](int g, float4* d) {
                uint4 i0 = *(const uint4*)&slO[p][g << 2];
                d[0] = *(const float4*)(WQ + i0.x);
                d[1] = *(const float4*)(WQ + i0.y);
                d[2] = *(const float4*)(WQ + i0.z);
                d[3] = *(const float4*)(WQ + i0.w);
            };
            auto acc4 = [&](const float4* d) {
#pragma unroll
                for (int u = 0; u < 4; ++u) {
                    rs.x += d[u].x; rs.y += d[u].y; rs.z += d[u].z; rs.w += d[u].w;
                }
            };
            int g = 0;
            if (ng > 0) ld4(0, b0);
            if (ng > 1) ld4(1, b1);
            while (g + 3 <= ng) {
                ld4(g + 2, b2);
                acc4(b0);                       // group g
                if (g + 3 < ng) ld4(g + 3, b0);
                acc4(b1);                       // group g+1
                if (g + 4 < ng) ld4(g + 4, b1);
                acc4(b2);                       // group g+2
                g += 3;
            }
            if (g < ng)     acc4(b0);           // group g
            if (g + 1 < ng) acc4(b1);           // group g+1
        }
        part[p][q] = rs;

        lds_barrier();   // B1: wmask + partials visible; slO fully consumed

        int total = 0;
#pragma unroll
        for (int w = 0; w < 8; ++w) total += __popcll(wmask[w]);

        if (st) {
            float rec = 0.f;
#pragma unroll
            for (int pp = 0; pp < 8; ++pp)
                rec += ((const float*)&part[pp][h >> 2])[h & 3];
            cur = (i_dec + ic_cur) + rec;
            if (zk) {
                int off = __popcll(m & ((1ull << lane) - 1ull));
#pragma unroll
                for (int w = 0; w < 8; ++w) if (w < wv) off += __popcll(wmask[w]);
                slN[off & 7][off >> 3] = (unsigned int)h << 11;
            }
        } else if (tid < HDIM + 32) {
            int s5 = (tid - HDIM) >> 2;
            int k  = (tid - HDIM) & 3;
            int ne = (total + 7 - s5) >> 3;
            int padc = (4 - (ne & 3)) & 3;
            if (k < padc) slN[s5][ne + k] = ZOFF;
        }
        cnt = total;
        ic_cur = ic_next;

        lds_barrier();   // B2: new lists complete before next step's gather

        unsigned int (*tp)[68] = slO; slO = slN; slN = tp;
    }
}

// ---------------------------------------------------------------------------
// Scan, bf16-weight path (flag==0 — dead on this harness, kept for safety).
// ---------------------------------------------------------------------------
__global__ __launch_bounds__(1024) void scan_bf16(const float* __restrict__ iin,
                                                  const unsigned short* __restrict__ WrecTb,
                                                  const int* __restrict__ flag,
                                                  unsigned long long* __restrict__ masksG) {
    if (*flag != 0) return;
    const int b    = blockIdx.x;
    const int tid  = threadIdx.x;
    const int q    = tid & 63;
    const int pc   = tid >> 6;
    const int lane = tid & 63;
    const int wv   = tid >> 6;
    const bool st  = tid < HDIM;
    const int h    = tid;

    __shared__ unsigned long long wmask[8];
    __shared__ float4 partA[16][64];
    __shared__ float4 partB[16][64];
    __shared__ alignas(16) unsigned int slA[16][36];
    __shared__ alignas(16) unsigned int slB[16][36];
    unsigned int (*slO)[36] = slA;
    unsigned int (*slN)[36] = slB;

    float v = 0.f, cur = 0.f, a = 0.f;
    int   cnt = 0;
    const char* WQ = (const char*)WrecTb + q * 16;
    float ic_cur = st ? iin[(size_t)b * HDIM + h] : 0.f;

    for (int t = 0; t < T_STEPS; ++t) {
        float ic_next = 0.f;
        if (st && (t + 1) < T_STEPS)
            ic_next = iin[((size_t)(t + 1) * BATCH + b) * HDIM + h];

        float i_dec = 0.f; bool zk = false; unsigned long long m = 0;
        if (st) {
            float s = (0.0f - v) + 0.5f * expf((v - 1.0f) * 2.0f);
            s = s + cur;
            s = s - a;
            float v_dec = v + 0.1f * s;
            i_dec = cur - 0.2f * cur;
            float a_dec = a + 0.002f * (4.0f * v - a);
            zk = (v_dec - 1.0f) > 0.0f;
            m = __ballot(zk);
            if (lane == 0) {
                wmask[wv] = m;
                masksG[((size_t)t * BATCH + b) * 8 + wv] = m;
            }
            v = zk ? 0.0f : v_dec;
            a = zk ? (a_dec + 0.02f) : a_dec;
        }

        float rs0=0.f,rs1=0.f,rs2=0.f,rs3=0.f,rs4=0.f,rs5=0.f,rs6=0.f,rs7=0.f;
        {
            const unsigned int* sl = slO[pc];
            const int n  = (cnt + 15 - pc) >> 4;
            const int ng = (n + 3) >> 2;
            uint4 w0[4], w1[4];
            auto ldg = [&](int g, uint4* w) {
                uint4 ix = *(const uint4*)(sl + (g << 2));
                w[0] = *(const uint4*)(WQ + ix.x);
                w[1] = *(const uint4*)(WQ + ix.y);
                w[2] = *(const uint4*)(WQ + ix.z);
                w[3] = *(const uint4*)(WQ + ix.w);
            };
            auto accw = [&](const uint4* w) {
#pragma unroll
                for (int u = 0; u < 4; ++u) {
                    rs0 += asf(w[u].x << 16); rs1 += asf(w[u].x & 0xffff0000u);
                    rs2 += asf(w[u].y << 16); rs3 += asf(w[u].y & 0xffff0000u);
                    rs4 += asf(w[u].z << 16); rs5 += asf(w[u].z & 0xffff0000u);
                    rs6 += asf(w[u].w << 16); rs7 += asf(w[u].w & 0xffff0000u);
                }
            };
            int g = 0;
            if (ng > 0) ldg(0, w0);
            while (g + 2 <= ng) {
                ldg(g + 1, w1);
                accw(w0);
                if (g + 2 < ng) ldg(g + 2, w0);
                accw(w1);
                g += 2;
            }
            if (g < ng) accw(w0);
        }
        partA[pc][q] = (float4){rs0, rs1, rs2, rs3};
        partB[pc][q] = (float4){rs4, rs5, rs6, rs7};

        lds_barrier();

        int total = 0;
#pragma unroll
        for (int w = 0; w < 8; ++w) total += __popcll(wmask[w]);

        if (st) {
            float rec = 0.f;
            const int  qq = h >> 3, jj = h & 3;
            const bool hi = (h & 4) != 0;
#pragma unroll
            for (int pp = 0; pp < 16; ++pp) {
                const float* pa = (const float*)&partA[pp][qq];
                const float* pb = (const float*)&partB[pp][qq];
                rec += hi ? pb[jj] : pa[jj];
            }
            cur = (i_dec + ic_cur) + rec;
            if (zk) {
                int off = __popcll(m & ((1ull << lane) - 1ull));
#pragma unroll
                for (int w = 0; w < 8; ++w) if (w < wv) off += __popcll(wmask[w]);
                slN[off & 15][off >> 4] = (unsigned int)h << 10;
            }
        } else if (tid < HDIM + 64) {
            int s5 = (tid - HDIM) >> 2;
            int k  = (tid - HDIM) & 3;
            int ne = (total + 15 - s5) >> 4;
            int padc = (4 - (ne & 3)) & 3;
            if (k < padc) slN[s5][ne + k] = ZOFFB;
        }
        cnt = total;
        ic_cur = ic_next;

        lds_barrier();

        unsigned int (*tp)[36] = slO; slO = slN; slN = tp;
    }
}

// ---------------------------------------------------------------------------
// Readout from spike masks: y[t][b][o] = sum_{h' spiking} WoutT[h'][o] + b[o]
// ---------------------------------------------------------------------------
__global__ __launch_bounds__(256) void y_kernel(const unsigned long long* __restrict__ masks,
                                                const float* __restrict__ WoutT,
                                                const float* __restrict__ bout,
                                                float* __restrict__ y) {
    const int tid = threadIdx.x;
    const int p   = blockIdx.x * 8 + (tid >> 5);   // t*BATCH + b
    const int o   = tid & 31;
    const unsigned long long* mp = masks + (size_t)p * 8;
    float acc = 0.f;
#pragma unroll
    for (int w = 0; w < 8; ++w) {
        unsigned long long m = mp[w];
        const float* Wb = WoutT + (size_t)w * 64 * ODIM + o;
        while (m) {
            int j = __builtin_ctzll(m);
            acc += Wb[j * ODIM];
            m &= m - 1;
        }
    }
    y[(size_t)p * ODIM + o] = acc + bout[o];
}

// ---------------------------------------------------------------------------
// Exponential filter over t: 4096 independent (b,o) chains; chunked prefetch.
// ---------------------------------------------------------------------------
__global__ __launch_bounds__(64) void filter_kernel(const float* __restrict__ y,
                                                    const int* __restrict__ flag,
                                                    void* __restrict__ out) {
    const int p = blockIdx.x * 64 + threadIdx.x;   // b*ODIM + o
    const int fp32o = *flag;
    const float kf = 0.2231435511314f;   // DT*TAU_FILTER_INV
    float c0[10], c1[10];
#pragma unroll
    for (int u = 0; u < 10; ++u) c0[u] = y[(size_t)u * (BATCH * ODIM) + p];
    float o_state = 0.f;
    for (int base = 0; base < T_STEPS; base += 10) {
        if (base + 10 < T_STEPS) {
#pragma unroll
            for (int u = 0; u < 10; ++u)
                c1[u] = y[(size_t)(base + 10 + u) * (BATCH * ODIM) + p];
        }
#pragma unroll
        for (int u = 0; u < 10; ++u) {
            int t = base + u;
            float yt = c0[u];
            o_state = (t == 0) ? yt : (o_state + kf * (yt - o_state));
            size_t oi = (size_t)t * (BATCH * ODIM) + p;
            if (fp32o) ((float*)out)[oi] = o_state;
            else       ((__hip_bfloat16*)out)[oi] = __float2bfloat16(o_state);
        }
#pragma unroll
        for (int u = 0; u < 10; ++u) c0[u] = c1[u];
    }
}

// ---------------------------------------------------------------------------
extern "C" void kernel_launch(void* const* d_in, const int* in_sizes, int n_in,
                              void* d_out, int out_size, void* d_ws, size_t ws_size,
                              hipStream_t stream) {
    // select inputs by unique element count (robust to ordering)
    const void* x = d_in[0]; const void* Win = d_in[1]; const void* Wrec = d_in[2];
    const void* Wout = d_in[3]; const void* bout = d_in[4];
    for (int i = 0; i < n_in; ++i) {
        switch (in_sizes[i]) {
            case 8192000: x    = d_in[i]; break;
            case 65536:   Win  = d_in[i]; break;
            case 262144:  Wrec = d_in[i]; break;
            case 16384:   Wout = d_in[i]; break;
            case 32:      bout = d_in[i]; break;
            default: break;
        }
    }

    // workspace layout (bytes) — WrecTb (bf16) aliases WrecT (fp32) storage
    const size_t OFF_FLAG  = 0;          // 4
    const size_t OFF_BOUT  = 256;        // 128
    const size_t OFF_WOUTT = 512;        // 65536
    const size_t OFF_WRECT = 66048;      // 513*512*4 = 1050624
    const size_t OFF_WINT  = 1116672;    // 262144
    const size_t OFF_MASK  = 1378816;    // 500*128*8*8 = 4096000
    const size_t OFF_IIN   = 5474816;    // 64000*512*4 = 131072000
    const size_t OFF_Y     = OFF_IIN;    // y (8.2 MB) aliases iin (dead after scan)
    const size_t REQUIRED  = OFF_IIN + (size_t)M_ROWS * HDIM * 4;  // 136546816
    if (ws_size < REQUIRED) return;  // diagnostic: output stays 0

    char* ws = (char*)d_ws;
    int*            flag   = (int*)(ws + OFF_FLAG);
    float*          bout32 = (float*)(ws + OFF_BOUT);
    float*          WoutT  = (float*)(ws + OFF_WOUTT);
    float*          WrecT  = (float*)(ws + OFF_WRECT);
    unsigned short* WrecTb = (unsigned short*)(ws + OFF_WRECT);
    float*          WinT   = (float*)(ws + OFF_WINT);
    unsigned long long* masks = (unsigned long long*)(ws + OFF_MASK);
    float*          iin    = (float*)(ws + OFF_IIN);
    float*          y      = (float*)(ws + OFF_Y);

    hipLaunchKernelGGL(detect_kernel, dim3(1), dim3(256), 0, stream,
                       (const unsigned short*)x, flag);
    hipLaunchKernelGGL(prep_kernel, dim3((HDIM * HDIM + 255) / 256), dim3(256), 0, stream,
                       Wrec, Wout, bout, Win, flag, WrecT, WrecTb, WoutT, WinT, bout32);
    hipLaunchKernelGGL(iin_gemm_mfma, dim3(M_ROWS / 64, HDIM / 64), dim3(256), 0, stream,
                       (const __hip_bfloat16*)x, (const __hip_bfloat16*)Win, flag, iin);
    hipLaunchKernelGGL(iin_gemm_valu, dim3(M_ROWS / 32), dim3(256), 0, stream,
                       x, WinT, flag, iin);
    hipLaunchKernelGGL(scan_f32, dim3(BATCH), dim3(1024), 0, stream,
                       iin, WrecT, flag, masks);
    hipLaunchKernelGGL(scan_bf16, dim3(BATCH), dim3(1024), 0, stream,
                       iin, WrecTb, flag, masks);
    hipLaunchKernelGGL(y_kernel, dim3(M_ROWS / 8), dim3(256), 0, stream,
                       masks, WoutT, bout32, y);
    hipLaunchKernelGGL(filter_kernel, dim3((BATCH * ODIM) / 64), dim3(64), 0, stream,
                       y, flag, d_out);
}

// Round 10
// 926.309 us; speedup vs baseline: 1.0108x; 1.0108x over previous
//
#include <hip/hip_runtime.h>
#include <hip/hip_bf16.h>
#include <cstdint>
#include <cstddef>

// Problem dims (fixed by reference)
#define T_STEPS 500
#define BATCH   128
#define FDIM    128
#define HDIM    512
#define ODIM    32
#define M_ROWS  (T_STEPS * BATCH)   // 64000
#define ZOFF    (512u << 11)        // zero-row byte offset, fp32 WrecT (2 KB rows)
#define ZOFFB   (512u << 10)        // zero-row byte offset, bf16 WrecTb (1 KB rows)

typedef __attribute__((ext_vector_type(8))) __bf16 bf16x8;
typedef __attribute__((ext_vector_type(4))) float  f32x4;

__device__ __forceinline__ float bfbits2f(unsigned short u) {
    union { unsigned int i; float f; } c; c.i = ((unsigned int)u) << 16; return c.f;
}
__device__ __forceinline__ float asf(unsigned int u) {
    union { unsigned int i; float f; } c; c.i = u; return c.f;
}

// ---------------------------------------------------------------------------
// Dtype detect: flag=1 -> fp32 inputs (measured live on this harness), 0 -> bf16.
// ---------------------------------------------------------------------------
__global__ void detect_kernel(const unsigned short* __restrict__ xw, int* __restrict__ flag) {
    __shared__ int cnt;
    if (threadIdx.x == 0) cnt = 0;
    __syncthreads();
    unsigned short w = xw[threadIdx.x * 2];
    int e = (w >> 7) & 0xFF;
    if (e >= 170) atomicAdd(&cnt, 1);
    __syncthreads();
    if (threadIdx.x == 0) *flag = (cnt >= 8) ? 1 : 0;
}

// ---------------------------------------------------------------------------
// Prep. flag==1 (fp32): WrecT fp32 transpose (+zero row).
//       flag==0 (bf16): WrecTb raw-bit transpose (+zero row).
// WoutT (fp32 [h][o]) and bout32 built either way. (Validated R8 call-1.)
// ---------------------------------------------------------------------------
__global__ void prep_kernel(const void* __restrict__ Wrec,
                            const void* __restrict__ Wout,
                            const void* __restrict__ bout,
                            const int* __restrict__ flag,
                            float* __restrict__ WrecT,
                            unsigned short* __restrict__ WrecTb,
                            float* __restrict__ WoutT,
                            float* __restrict__ bout32) {
    const int fp32 = *flag;
    int idx = blockIdx.x * blockDim.x + threadIdx.x;
    if (fp32) {
        if (idx < HDIM * HDIM) {
            int h = idx / HDIM, hp = idx % HDIM;
            WrecT[hp * HDIM + h] = ((const float*)Wrec)[idx];
        }
        if (idx < HDIM) WrecT[HDIM * HDIM + idx] = 0.f;
    } else {
        if (idx < HDIM * HDIM) {
            int h = idx / HDIM, hp = idx % HDIM;
            WrecTb[hp * HDIM + h] = ((const unsigned short*)Wrec)[idx];
        }
        if (idx < HDIM) WrecTb[HDIM * HDIM + idx] = 0;
    }
    if (idx < ODIM * HDIM) {
        int o = idx / HDIM, h = idx % HDIM;
        WoutT[h * ODIM + o] = fp32 ? ((const float*)Wout)[idx]
                                   : bfbits2f(((const unsigned short*)Wout)[idx]);
    }
    if (idx < ODIM)
        bout32[idx] = fp32 ? ((const float*)bout)[idx]
                           : bfbits2f(((const unsigned short*)bout)[idx]);
}

// ---------------------------------------------------------------------------
// i_in GEMM, MFMA path (flag==0 / bf16 only — dead on this harness).
// ---------------------------------------------------------------------------
__global__ __launch_bounds__(256) void iin_gemm_mfma(const __hip_bfloat16* __restrict__ x,
                                                     const __hip_bfloat16* __restrict__ Win,
                                                     const int* __restrict__ flag,
                                                     float* __restrict__ iin) {
    if (*flag != 0) return;
    const int mt   = blockIdx.x;
    const int nt   = blockIdx.y;
    const int wave = threadIdx.x >> 6;
    const int lane = threadIdx.x & 63;
    const int l15  = lane & 15;
    const int quad = lane >> 4;
    const int m_base = mt * 64 + wave * 16;
    const int n_base = nt * 64;

    const __bf16* xb = reinterpret_cast<const __bf16*>(x);
    const __bf16* wb = reinterpret_cast<const __bf16*>(Win);

    f32x4 acc[4] = {{0.f,0.f,0.f,0.f},{0.f,0.f,0.f,0.f},{0.f,0.f,0.f,0.f},{0.f,0.f,0.f,0.f}};

#pragma unroll
    for (int kk = 0; kk < 4; ++kk) {
        const int k0 = kk * 32 + quad * 8;
        bf16x8 a = *reinterpret_cast<const bf16x8*>(xb + (size_t)(m_base + l15) * FDIM + k0);
#pragma unroll
        for (int nb = 0; nb < 4; ++nb) {
            bf16x8 bf = *reinterpret_cast<const bf16x8*>(wb + (size_t)(n_base + nb * 16 + l15) * FDIM + k0);
            acc[nb] = __builtin_amdgcn_mfma_f32_16x16x32_bf16(a, bf, acc[nb], 0, 0, 0);
        }
    }

#pragma unroll
    for (int nb = 0; nb < 4; ++nb)
#pragma unroll
        for (int r = 0; r < 4; ++r)
            iin[(size_t)(m_base + quad * 4 + r) * HDIM + n_base + nb * 16 + l15] = acc[nb][r];
}

// ---------------------------------------------------------------------------
// i_in GEMM v3, fp32 VALU (flag==1, LIVE; validated R8 call-1, deterministic).
// ---------------------------------------------------------------------------
__global__ __launch_bounds__(256) void iin_gemm_valu(const float* __restrict__ x,
                                                     const float* __restrict__ Win,
                                                     const int* __restrict__ flag,
                                                     float* __restrict__ iin) {
    if (*flag != 1) return;
    const int tid = threadIdx.x;
    const int m0  = blockIdx.x * 32;

    __shared__ float xs[32][FDIM];   // 16 KB

    {   // coalesced float4 staging of 32 x-rows
        const float4* src = (const float4*)(x + (size_t)m0 * FDIM);
        float4* dst = (float4*)&xs[0][0];
        for (int i = tid; i < 32 * FDIM / 4; i += 256) dst[i] = src[i];
    }
    __syncthreads();

    const float4* w0p = (const float4*)(Win + (size_t)tid * FDIM);
    const float4* w1p = (const float4*)(Win + (size_t)(tid + 256) * FDIM);

    float acc[32][2];
#pragma unroll
    for (int m = 0; m < 32; ++m) { acc[m][0] = 0.f; acc[m][1] = 0.f; }

    for (int k4 = 0; k4 < FDIM / 4; ++k4) {
        float4 w0 = w0p[k4];
        float4 w1 = w1p[k4];
#pragma unroll
        for (int m = 0; m < 32; ++m) {
            float4 xv = *(const float4*)&xs[m][k4 * 4];
            float a0 = acc[m][0], a1 = acc[m][1];
            a0 += xv.x * w0.x; a0 += xv.y * w0.y; a0 += xv.z * w0.z; a0 += xv.w * w0.w;
            a1 += xv.x * w1.x; a1 += xv.y * w1.y; a1 += xv.z * w1.z; a1 += xv.w * w1.w;
            acc[m][0] = a0; acc[m][1] = a1;
        }
    }

#pragma unroll
    for (int m = 0; m < 32; ++m) {
        iin[(size_t)(m0 + m) * HDIM + tid]       = acc[m][0];
        iin[(size_t)(m0 + m) * HDIM + 256 + tid] = acc[m][1];
    }
}

// ---------------------------------------------------------------------------
// Scan (flag==1, LIVE) — VERBATIM the R5/R6 kernel that passed twice with
// replay-stable results (648 µs). Two __syncthreads per step; mod-8 parity
// sub-lists; popc-prefix scatter post-B1; ZOFF padding. One-barrier variants
// (R8 atomic, R9 ping-pong) both failed on HW despite paper proofs — the
// two-barrier skeleton is the empirically safe structure. DO NOT single-barrier.
// ---------------------------------------------------------------------------
__global__ __launch_bounds__(1024) void scan_f32(const float* __restrict__ iin,
                                                 const float* __restrict__ WrecT,
                                                 const int* __restrict__ flag,
                                                 unsigned long long* __restrict__ masksG) {
    if (*flag != 1) return;
    const int b    = blockIdx.x;
    const int tid  = threadIdx.x;
    const int q    = tid & 127;
    const int p    = tid >> 7;
    const int lane = tid & 63;
    const int wv   = tid >> 6;
    const bool st  = tid < HDIM;
    const int h    = tid;

    __shared__ unsigned long long wmask[8];
    __shared__ float4 part[8][128];
    __shared__ alignas(16) unsigned int slA[8][68];
    __shared__ alignas(16) unsigned int slB[8][68];
    unsigned int (*slO)[68] = slA;
    unsigned int (*slN)[68] = slB;

    float v = 0.f, cur = 0.f, a = 0.f;
    int   cnt = 0;
    const char* WQ = (const char*)WrecT + q * 16;

    for (int t = 0; t < T_STEPS; ++t) {
        float ic = 0.f, i_dec = 0.f;
        bool  zk = false;
        unsigned long long m = 0;

        if (st) {
            ic = iin[((size_t)t * BATCH + b) * HDIM + h];
            float s = (0.0f - v) + 0.5f * expf((v - 1.0f) * 2.0f);
            s = s + cur;
            s = s - a;
            float v_dec = v + 0.1f * s;
            i_dec = cur - 0.2f * cur;
            float a_dec = a + 0.002f * (4.0f * v - a);
            zk = (v_dec - 1.0f) > 0.0f;
            m = __ballot(zk);
            if (lane == 0) {
                wmask[wv] = m;
                masksG[((size_t)t * BATCH + b) * 8 + wv] = m;
            }
            v = zk ? 0.0f : v_dec;
            a = zk ? (a_dec + 0.02f) : a_dec;
        }

        float4 rs = {0.f, 0.f, 0.f, 0.f};
        {
            const int n  = (cnt + 7 - p) >> 3;
            const int ng = (n + 3) >> 2;
            float4 b0[4], b1[4];
            auto ld4 = [&](int g, float4* d) {
                uint4 i0 = *(const uint4*)&slO[p][g << 2];
                d[0] = *(const float4*)(WQ + i0.x);
                d[1] = *(const float4*)(WQ + i0.y);
                d[2] = *(const float4*)(WQ + i0.z);
                d[3] = *(const float4*)(WQ + i0.w);
            };
            auto acc4 = [&](const float4* d) {
#pragma unroll
                for (int u = 0; u < 4; ++u) {
                    rs.x += d[u].x; rs.y += d[u].y; rs.z += d[u].z; rs.w += d[u].w;
                }
            };
            int g = 0;
            if (ng > 0) ld4(0, b0);
            while (g + 2 <= ng) {
                ld4(g + 1, b1);
                acc4(b0);
                if (g + 2 < ng) ld4(g + 2, b0);
                acc4(b1);
                g += 2;
            }
            if (g < ng) acc4(b0);
        }
        part[p][q] = rs;

        __syncthreads();

        int total = 0;
#pragma unroll
        for (int w = 0; w < 8; ++w) total += __popcll(wmask[w]);

        if (st) {
            float rec = 0.f;
#pragma unroll
            for (int pp = 0; pp < 8; ++pp)
                rec += ((const float*)&part[pp][h >> 2])[h & 3];
            cur = (i_dec + ic) + rec;
            if (zk) {
                int off = __popcll(m & ((1ull << lane) - 1ull));
#pragma unroll
                for (int w = 0; w < 8; ++w) if (w < wv) off += __popcll(wmask[w]);
                slN[off & 7][off >> 3] = (unsigned int)h << 11;
            }
        } else if (tid < HDIM + 32) {
            int s5 = (tid - HDIM) >> 2;
            int k  = (tid - HDIM) & 3;
            int ne = (total + 7 - s5) >> 3;
            int padc = (4 - (ne & 3)) & 3;
            if (k < padc) slN[s5][ne + k] = ZOFF;
        }
        cnt = total;

        __syncthreads();

        unsigned int (*tp)[68] = slO; slO = slN; slN = tp;
    }
}

// ---------------------------------------------------------------------------
// Scan, bf16-weight path (flag==0 — dead on this harness, kept for safety).
// ---------------------------------------------------------------------------
__global__ __launch_bounds__(1024) void scan_bf16(const float* __restrict__ iin,
                                                  const unsigned short* __restrict__ WrecTb,
                                                  const int* __restrict__ flag,
                                                  unsigned long long* __restrict__ masksG) {
    if (*flag != 0) return;
    const int b    = blockIdx.x;
    const int tid  = threadIdx.x;
    const int q    = tid & 63;
    const int pc   = tid >> 6;
    const int lane = tid & 63;
    const int wv   = tid >> 6;
    const bool st  = tid < HDIM;
    const int h    = tid;

    __shared__ unsigned long long wmask[8];
    __shared__ float4 partA[16][64];
    __shared__ float4 partB[16][64];
    __shared__ alignas(16) unsigned int slA[16][36];
    __shared__ alignas(16) unsigned int slB[16][36];
    unsigned int (*slO)[36] = slA;
    unsigned int (*slN)[36] = slB;

    float v = 0.f, cur = 0.f, a = 0.f;
    int   cnt = 0;
    const char* WQ = (const char*)WrecTb + q * 16;

    for (int t = 0; t < T_STEPS; ++t) {
        float ic = 0.f, i_dec = 0.f; bool zk = false; unsigned long long m = 0;
        if (st) {
            ic = iin[((size_t)t * BATCH + b) * HDIM + h];
            float s = (0.0f - v) + 0.5f * expf((v - 1.0f) * 2.0f);
            s = s + cur;
            s = s - a;
            float v_dec = v + 0.1f * s;
            i_dec = cur - 0.2f * cur;
            float a_dec = a + 0.002f * (4.0f * v - a);
            zk = (v_dec - 1.0f) > 0.0f;
            m = __ballot(zk);
            if (lane == 0) {
                wmask[wv] = m;
                masksG[((size_t)t * BATCH + b) * 8 + wv] = m;
            }
            v = zk ? 0.0f : v_dec;
            a = zk ? (a_dec + 0.02f) : a_dec;
        }

        float rs0=0.f,rs1=0.f,rs2=0.f,rs3=0.f,rs4=0.f,rs5=0.f,rs6=0.f,rs7=0.f;
        {
            const unsigned int* sl = slO[pc];
            const int n  = (cnt + 15 - pc) >> 4;
            const int ng = (n + 3) >> 2;
            uint4 w0[4], w1[4];
            auto ldg = [&](int g, uint4* w) {
                uint4 ix = *(const uint4*)(sl + (g << 2));
                w[0] = *(const uint4*)(WQ + ix.x);
                w[1] = *(const uint4*)(WQ + ix.y);
                w[2] = *(const uint4*)(WQ + ix.z);
                w[3] = *(const uint4*)(WQ + ix.w);
            };
            auto accw = [&](const uint4* w) {
#pragma unroll
                for (int u = 0; u < 4; ++u) {
                    rs0 += asf(w[u].x << 16); rs1 += asf(w[u].x & 0xffff0000u);
                    rs2 += asf(w[u].y << 16); rs3 += asf(w[u].y & 0xffff0000u);
                    rs4 += asf(w[u].z << 16); rs5 += asf(w[u].z & 0xffff0000u);
                    rs6 += asf(w[u].w << 16); rs7 += asf(w[u].w & 0xffff0000u);
                }
            };
            int g = 0;
            if (ng > 0) ldg(0, w0);
            while (g + 2 <= ng) {
                ldg(g + 1, w1);
                accw(w0);
                if (g + 2 < ng) ldg(g + 2, w0);
                accw(w1);
                g += 2;
            }
            if (g < ng) accw(w0);
        }
        partA[pc][q] = (float4){rs0, rs1, rs2, rs3};
        partB[pc][q] = (float4){rs4, rs5, rs6, rs7};

        __syncthreads();

        int total = 0;
#pragma unroll
        for (int w = 0; w < 8; ++w) total += __popcll(wmask[w]);

        if (st) {
            float rec = 0.f;
            const int  qq = h >> 3, jj = h & 3;
            const bool hi = (h & 4) != 0;
#pragma unroll
            for (int pp = 0; pp < 16; ++pp) {
                const float* pa = (const float*)&partA[pp][qq];
                const float* pb = (const float*)&partB[pp][qq];
                rec += hi ? pb[jj] : pa[jj];
            }
            cur = (i_dec + ic) + rec;
            if (zk) {
                int off = __popcll(m & ((1ull << lane) - 1ull));
#pragma unroll
                for (int w = 0; w < 8; ++w) if (w < wv) off += __popcll(wmask[w]);
                slN[off & 15][off >> 4] = (unsigned int)h << 10;
            }
        } else if (tid < HDIM + 64) {
            int s5 = (tid - HDIM) >> 2;
            int k  = (tid - HDIM) & 3;
            int ne = (total + 15 - s5) >> 4;
            int padc = (4 - (ne & 3)) & 3;
            if (k < padc) slN[s5][ne + k] = ZOFFB;
        }
        cnt = total;

        __syncthreads();

        unsigned int (*tp)[36] = slO; slO = slN; slN = tp;
    }
}

// ---------------------------------------------------------------------------
// Readout from spike masks: y[t][b][o] = sum_{h' spiking} WoutT[h'][o] + b[o]
// ---------------------------------------------------------------------------
__global__ __launch_bounds__(256) void y_kernel(const unsigned long long* __restrict__ masks,
                                                const float* __restrict__ WoutT,
                                                const float* __restrict__ bout,
                                                float* __restrict__ y) {
    const int tid = threadIdx.x;
    const int p   = blockIdx.x * 8 + (tid >> 5);   // t*BATCH + b
    const int o   = tid & 31;
    const unsigned long long* mp = masks + (size_t)p * 8;
    float acc = 0.f;
#pragma unroll
    for (int w = 0; w < 8; ++w) {
        unsigned long long m = mp[w];
        const float* Wb = WoutT + (size_t)w * 64 * ODIM + o;
        while (m) {
            int j = __builtin_ctzll(m);
            acc += Wb[j * ODIM];
            m &= m - 1;
        }
    }
    y[(size_t)p * ODIM + o] = acc + bout[o];
}

// ---------------------------------------------------------------------------
// Exponential filter over t: 4096 independent (b,o) chains; chunked prefetch.
// ---------------------------------------------------------------------------
__global__ __launch_bounds__(64) void filter_kernel(const float* __restrict__ y,
                                                    const int* __restrict__ flag,
                                                    void* __restrict__ out) {
    const int p = blockIdx.x * 64 + threadIdx.x;   // b*ODIM + o
    const int fp32o = *flag;
    const float kf = 0.2231435511314f;   // DT*TAU_FILTER_INV
    float c0[10], c1[10];
#pragma unroll
    for (int u = 0; u < 10; ++u) c0[u] = y[(size_t)u * (BATCH * ODIM) + p];
    float o_state = 0.f;
    for (int base = 0; base < T_STEPS; base += 10) {
        if (base + 10 < T_STEPS) {
#pragma unroll
            for (int u = 0; u < 10; ++u)
                c1[u] = y[(size_t)(base + 10 + u) * (BATCH * ODIM) + p];
        }
#pragma unroll
        for (int u = 0; u < 10; ++u) {
            int t = base + u;
            float yt = c0[u];
            o_state = (t == 0) ? yt : (o_state + kf * (yt - o_state));
            size_t oi = (size_t)t * (BATCH * ODIM) + p;
            if (fp32o) ((float*)out)[oi] = o_state;
            else       ((__hip_bfloat16*)out)[oi] = __float2bfloat16(o_state);
        }
#pragma unroll
        for (int u = 0; u < 10; ++u) c0[u] = c1[u];
    }
}

// ---------------------------------------------------------------------------
extern "C" void kernel_launch(void* const* d_in, const int* in_sizes, int n_in,
                              void* d_out, int out_size, void* d_ws, size_t ws_size,
                              hipStream_t stream) {
    // select inputs by unique element count (robust to ordering)
    const void* x = d_in[0]; const void* Win = d_in[1]; const void* Wrec = d_in[2];
    const void* Wout = d_in[3]; const void* bout = d_in[4];
    for (int i = 0; i < n_in; ++i) {
        switch (in_sizes[i]) {
            case 8192000: x    = d_in[i]; break;
            case 65536:   Win  = d_in[i]; break;
            case 262144:  Wrec = d_in[i]; break;
            case 16384:   Wout = d_in[i]; break;
            case 32:      bout = d_in[i]; break;
            default: break;
        }
    }

    // workspace layout (bytes) — WrecTb (bf16) aliases WrecT (fp32) storage
    const size_t OFF_FLAG  = 0;          // 4
    const size_t OFF_BOUT  = 256;        // 128
    const size_t OFF_WOUTT = 512;        // 65536
    const size_t OFF_WRECT = 66048;      // 513*512*4 = 1050624
    const size_t OFF_MASK  = 1378816;    // 500*128*8*8 = 4096000
    const size_t OFF_IIN   = 5474816;    // 64000*512*4 = 131072000
    const size_t OFF_Y     = OFF_IIN;    // y (8.2 MB) aliases iin (dead after scan)
    const size_t REQUIRED  = OFF_IIN + (size_t)M_ROWS * HDIM * 4;  // 136546816
    if (ws_size < REQUIRED) return;  // diagnostic: output stays 0

    char* ws = (char*)d_ws;
    int*            flag   = (int*)(ws + OFF_FLAG);
    float*          bout32 = (float*)(ws + OFF_BOUT);
    float*          WoutT  = (float*)(ws + OFF_WOUTT);
    float*          WrecT  = (float*)(ws + OFF_WRECT);
    unsigned short* WrecTb = (unsigned short*)(ws + OFF_WRECT);
    unsigned long long* masks = (unsigned long long*)(ws + OFF_MASK);
    float*          iin    = (float*)(ws + OFF_IIN);
    float*          y      = (float*)(ws + OFF_Y);

    hipLaunchKernelGGL(detect_kernel, dim3(1), dim3(256), 0, stream,
                       (const unsigned short*)x, flag);
    hipLaunchKernelGGL(prep_kernel, dim3((HDIM * HDIM + 255) / 256), dim3(256), 0, stream,
                       Wrec, Wout, bout, flag, WrecT, WrecTb, WoutT, bout32);
    hipLaunchKernelGGL(iin_gemm_mfma, dim3(M_ROWS / 64, HDIM / 64), dim3(256), 0, stream,
                       (const __hip_bfloat16*)x, (const __hip_bfloat16*)Win, flag, iin);
    hipLaunchKernelGGL(iin_gemm_valu, dim3(M_ROWS / 32), dim3(256), 0, stream,
                       (const float*)x, (const float*)Win, flag, iin);
    hipLaunchKernelGGL(scan_f32, dim3(BATCH), dim3(1024), 0, stream,
                       iin, WrecT, flag, masks);
    hipLaunchKernelGGL(scan_bf16, dim3(BATCH), dim3(1024), 0, stream,
                       iin, WrecTb, flag, masks);
    hipLaunchKernelGGL(y_kernel, dim3(M_ROWS / 8), dim3(256), 0, stream,
                       masks, WoutT, bout32, y);
    hipLaunchKernelGGL(filter_kernel, dim3((BATCH * ODIM) / 64), dim3(64), 0, stream,
                       y, flag, d_out);
}